// Round 1
// baseline (85.144 us; speedup 1.0000x reference)
//
#include <hip/hip_runtime.h>
#include <math.h>

#define N_BOXES 10647
#define NUM_CLASSES 80
#define MAX_BOXES 20
#define IOU_T 0.1f
#define SCORE_T 0.3f

#define NT 1024
#define NWAVES (NT / 64)
#define KP 11      // ceil(N_BOXES / NT): per-thread candidate slots
#define WCAP 128   // window capacity (LDS)
#define TGT 96     // target window size (expected examine ~40 for 20 keeps)

#define CPBLOCKS 6  // boxes-copy blocks (run concurrently with NMS blocks)

// Output layout (all float32, concatenated):
//   [0)      boxes copy        N_BOXES*4               = 42588
//   [42588)  scores transposed NUM_CLASSES*N_BOXES     = 851760
//   [894348) nms_final         NUM_CLASSES*MAX_BOXES*3 = 4800
#define OUT_OFF_SCORES (N_BOXES * 4)
#define OUT_OFF_NMS (N_BOXES * 4 + NUM_CLASSES * N_BOXES)

// R14: single fused launch. The old 2-kernel pipeline serialized
// (transpose -> NMS reads transposed) purely so Phase A could read
// coalesced. But scores is 3.4 MB (L2-resident): the NMS block can read
// its column STRIDED from the original layout (same 64B lines shared by
// 16 classes; XCD-affine class permutation keeps line-sharing classes on
// the same XCD L2) and emit the transposed column itself with coalesced
// writes. Removes one launch + the inter-kernel drain entirely.
#define FOR_K(OP) OP(0) OP(1) OP(2) OP(3) OP(4) OP(5) OP(6) OP(7) OP(8) OP(9) OP(10)

// Reference-exact IoU>T test (individually rounded float32 ops; inter==0 =>
// reference IoU is 0 => not suppressed, divide skipped). First box is the
// SELECTED box (reference's area1 = selected's area, added first).
__device__ __forceinline__ bool iou_gt(float jy1, float jx1, float jy2,
                                       float jx2, float area_j, float4 b) {
    float ty = fmaxf(jy1, b.x);
    float tx = fmaxf(jx1, b.y);
    float by = fminf(jy2, b.z);
    float bx = fminf(jx2, b.w);
    float dy = fmaxf(__fsub_rn(by, ty), 0.0f);
    float dx = fmaxf(__fsub_rn(bx, tx), 0.0f);
    float inter = __fmul_rn(dy, dx);
    if (!(inter > 0.0f)) return false;
    float area_i = __fmul_rn(__fsub_rn(b.z, b.x), __fsub_rn(b.w, b.y));
    float uni = __fsub_rn(__fadd_rn(area_j, area_i), inter);
    float iou = (uni > 0.0f) ? __fdiv_rn(inter, uni) : 0.0f;
    return iou > IOU_T;
}

// ---------------------------------------------------------------------------
// Fused kernel: block-role split.
//   blocks [0, NUM_CLASSES)              : per-class NMS + transposed-column
//                                          emit (strided read, coalesced write)
//   blocks [NUM_CLASSES, +CPBLOCKS)      : boxes copy
// ---------------------------------------------------------------------------
__global__ __launch_bounds__(NT) void fused_nms_kernel(
    const float* __restrict__ boxes, const float* __restrict__ scores,
    float* __restrict__ out) {
    const int tid = threadIdx.x;
    const int b = blockIdx.x;

    if (b >= NUM_CLASSES) {
        // ---- boxes copy: 10647 float4s, coalesced both sides ----
        for (int q = (b - NUM_CLASSES) * NT + tid; q < N_BOXES;
             q += CPBLOCKS * NT) {
            ((float4*)out)[q] = ((const float4*)boxes)[q];
        }
        return;
    }

    // XCD-affine class permutation: default dispatch maps block b to XCD
    // b%8. Give XCD x classes x*10 .. x*10+9 so the strided column reads
    // of co-resident blocks share L2 lines (16 classes per 64B line).
    const int c = (b & 7) * 10 + (b >> 3);

    const int wave = tid >> 6;
    const int lane = tid & 63;
    const float4* boxes4 = (const float4*)boxes;
    const float* scol = scores + c;                       // stride-80 column
    float* tcol = out + OUT_OFF_SCORES + c * N_BOXES;     // contiguous out col

    __shared__ int s_hist[2048];                    // 8 KB
    __shared__ unsigned long long s_k[WCAP];        // 1 KB window keys
    __shared__ float4 s_b4[WCAP];                   // 2 KB window boxes
    __shared__ unsigned long long s_ks[WCAP];       // 1 KB sorted keys
    __shared__ float4 s_bs[WCAP];                   // 2 KB sorted boxes
    __shared__ __align__(16) unsigned long long s_mask[WCAP][2];  // 2 KB
    __shared__ unsigned long long s_rk[2][NWAVES];  // fallback reduce
    __shared__ int s_out[MAX_BOXES];
    __shared__ int s_bstar, s_total, s_cnt, s_nsel;

    if (tid < MAX_BOXES) s_out[tid] = -1;
    if (tid == 0) { s_cnt = 0; s_nsel = 0; }
    s_hist[tid] = 0;
    s_hist[tid + NT] = 0;
    __syncthreads();

    // ---- Phase A: strided column read (L2-resident) -> transposed-column
    // write (coalesced) + keys + histogram.
    // key = (score_bits << 32) | (0xFFFFFFFF - idx): u64 max == max score,
    // tie -> lowest index (jnp.argmax first-occurrence). 0 = invalid.
#define DECL_K(k) unsigned long long k_##k = 0;
    FOR_K(DECL_K)
#undef DECL_K
#define BUILD_K(k)                                                     \
    {                                                                  \
        int i = tid + (k)*NT;                                          \
        if (i < N_BOXES) {                                             \
            float v = scol[i * NUM_CLASSES];                           \
            tcol[i] = v;                                               \
            if (v >= SCORE_T) {                                        \
                unsigned int vb = __float_as_uint(v);                  \
                k_##k = ((unsigned long long)vb << 32) |               \
                        (0xFFFFFFFFu - (unsigned int)i);               \
                atomicAdd(&s_hist[(vb - 0x3E800000u) >> 13], 1);       \
            }                                                          \
        }                                                              \
    }
    FOR_K(BUILD_K)
#undef BUILD_K
    __syncthreads();

    // ---- Phase B (wave 0, fully parallel): b* = max bin with
    // suffix-count >= TGT (0 if total < TGT).
    if (wave == 0) {
        int lsum = 0;
        #pragma unroll
        for (int t = 0; t < 32; ++t) {
            int bb = (t + lane) & 31;  // rotate -> conflict-free banks
            lsum += s_hist[lane * 32 + bb];
        }
        int S = lsum;  // inclusive suffix over lanes (lane l: bins >= l*32)
        #pragma unroll
        for (int off = 1; off < 64; off <<= 1) {
            int up = __shfl_down(S, off);
            if (lane + off < 64) S += up;
        }
        unsigned long long mk = __ballot(S >= TGT);
        int bstar = 0;
        if (mk != 0) {
            const int L = 63 - __builtin_clzll(mk);
            const int S_L = __shfl(S, L);
            const int lsum_L = __shfl(lsum, L);
            const int S_above = S_L - lsum_L;  // suffix above lane L's bins
            int h = (lane < 32) ? s_hist[L * 32 + lane] : 0;
            int sfx = h;
            #pragma unroll
            for (int off = 1; off < 64; off <<= 1) {
                int up = __shfl_down(sfx, off);
                if (lane + off < 64) sfx += up;
            }
            unsigned long long sel = __ballot(sfx + S_above >= TGT);
            bstar = L * 32 + (63 - __builtin_clzll(sel));
        }
        if (lane == 0) {
            s_bstar = bstar;
            s_total = S;  // lane0 inclusive suffix == grand total
        }
    }
    __syncthreads();

    const unsigned int tbits = 0x3E800000u + ((unsigned int)s_bstar << 13);

    // ---- Phase C: compact window (score_bits >= tbits) into LDS ----
#define COMPACT_K(k)                                                    \
    {                                                                   \
        bool p = (k_##k != 0) &&                                        \
                 ((unsigned int)(k_##k >> 32) >= tbits);                \
        unsigned long long m = __ballot(p);                             \
        int basew = 0;                                                  \
        if (lane == 0 && m) basew = atomicAdd(&s_cnt, __popcll(m));     \
        basew = __shfl(basew, 0);                                       \
        if (p) {                                                        \
            int pos = basew + __popcll(m & ((1ull << lane) - 1ull));    \
            if (pos < WCAP) {                                           \
                s_k[pos] = k_##k;                                       \
                s_b4[pos] = boxes4[0xFFFFFFFFu - (unsigned int)k_##k];  \
            }                                                           \
        }                                                               \
    }
    FOR_K(COMPACT_K)
#undef COMPACT_K
    __syncthreads();

    const int wcnt = s_cnt;
    const bool overflow = (wcnt > WCAP);  // pathological ties only

    // ---- Phase D1: parallel rank sort of the window (threads 0..wcnt).
    // rank_i = #{j : key_j > key_i}; keys unique -> permutation. Broadcast
    // LDS reads, conflict-free.
    if (!overflow && tid < wcnt) {
        const unsigned long long mykey = s_k[tid];
        const float4 mybox = s_b4[tid];
        int rank = 0;
        for (int j = 0; j < wcnt; ++j) rank += (s_k[j] > mykey) ? 1 : 0;
        s_ks[rank] = mykey;
        s_bs[rank] = mybox;
    }
    __syncthreads();

    // ---- Phase D2: parallel suppression bit-matrix. Task t = (row,chunk):
    // lane computes iou_gt(row, chunk*64+lane); one ballot per task; all 16
    // waves work concurrently. Row = selected-box role (reference op order).
    if (!overflow) {
        const int ntask = 2 * wcnt;
        for (int t = wave; t < ntask; t += NWAVES) {
            const int row = t >> 1, ch = t & 1;
            float4 rb = s_bs[row];
            float area_r =
                __fmul_rn(__fsub_rn(rb.z, rb.x), __fsub_rn(rb.w, rb.y));
            int colj = ch * 64 + lane;
            bool s = (colj < wcnt) &&
                     iou_gt(rb.x, rb.y, rb.z, rb.w, area_r, s_bs[colj]);
            unsigned long long m = __ballot(s);
            if (lane == 0) s_mask[row][ch] = m;
        }
    }
    __syncthreads();

    // ---- Phase D3: serial resolve (wave 0, all lanes lockstep; pure
    // bit-ops + one broadcast ds_read_b128 per kept box).
    if (wave == 0 && !overflow) {
        unsigned long long a0, a1;
        if (wcnt >= 64) {
            a0 = ~0ull;
            a1 = (wcnt >= 128) ? ~0ull
                               : ((wcnt > 64) ? ((1ull << (wcnt - 64)) - 1)
                                              : 0ull);
        } else {
            a0 = (wcnt > 0) ? ((1ull << wcnt) - 1) : 0ull;
            a1 = 0ull;
        }
        int nkept = 0;
        while ((a0 | a1) != 0 && nkept < MAX_BOXES) {
            int pos = a0 ? __builtin_ctzll(a0)
                         : 64 + __builtin_ctzll(a1);
            if (lane == 0)
                s_out[nkept] =
                    (int)(0xFFFFFFFFu - (unsigned int)s_ks[pos]);
            ++nkept;
            ulonglong2 m = *(const ulonglong2*)&s_mask[pos][0];
            a0 &= ~m.x;
            a1 &= ~m.y;
            // insurance vs infinite loop (self-IoU is 1 > T, but be safe):
            if (pos < 64) a0 &= ~(1ull << pos);
            else a1 &= ~(1ull << (pos - 64));
        }
        if (lane == 0) s_nsel = nkept;
    }
    __syncthreads();

    // ---- Phase E: exact fallback (window exhausted early / overflow).
    // Invariant: if !overflow and nsel0 < 20, every window member was
    // examined (kept or suppressed) -> all dead; non-members re-checked
    // against the selected set. Never triggers on typical data.
    const int nsel0 = s_nsel;
    const bool needs_more =
        (nsel0 < MAX_BOXES) && (overflow || (wcnt < s_total));
    if (needs_more) {
#define LIVE_K(k)                                                        \
        if (k_##k != 0) {                                                \
            bool dead =                                                  \
                (!overflow &&                                            \
                 ((unsigned int)(k_##k >> 32) >= tbits));                \
            if (!dead && nsel0 > 0) {                                    \
                int i = tid + (k)*NT;                                    \
                float4 bi = boxes4[i];                                   \
                for (int j = 0; j < nsel0; ++j) {                        \
                    float4 sb = boxes4[s_out[j]];                        \
                    float aj = __fmul_rn(__fsub_rn(sb.z, sb.x),          \
                                         __fsub_rn(sb.w, sb.y));         \
                    if (iou_gt(sb.x, sb.y, sb.z, sb.w, aj, bi)) {        \
                        dead = true;                                     \
                        break;                                           \
                    }                                                    \
                }                                                        \
            }                                                            \
            if (dead) k_##k = 0;                                         \
        }
        FOR_K(LIVE_K)
#undef LIVE_K
        for (int slot = nsel0; slot < MAX_BOXES; ++slot) {
            unsigned long long bk = 0;
#define MAXK_K(k) if (k_##k > bk) bk = k_##k;
            FOR_K(MAXK_K)
#undef MAXK_K
            #pragma unroll
            for (int off = 32; off >= 1; off >>= 1) {
                unsigned long long o =
                    (unsigned long long)__shfl_xor((long long)bk, off);
                if (o > bk) bk = o;
            }
            const int par = slot & 1;
            if (lane == 0) s_rk[par][wave] = bk;
            __syncthreads();
            unsigned long long f = s_rk[par][0];
            #pragma unroll
            for (int w = 1; w < NWAVES; ++w) {
                unsigned long long o = s_rk[par][w];
                if (o > f) f = o;
            }
            if (f == 0) break;  // uniform
            const int widx = (int)(0xFFFFFFFFu - (unsigned int)f);
            if (tid == 0) s_out[slot] = widx;
            float4 wb = boxes4[widx];  // uniform L1 broadcast
            const float area_j =
                __fmul_rn(__fsub_rn(wb.z, wb.x), __fsub_rn(wb.w, wb.y));
#define SCANE_K(k)                                                      \
            if (k_##k != 0) {                                           \
                int i = tid + (k)*NT;                                   \
                float4 b = boxes4[i];                                   \
                if (i == widx ||                                        \
                    iou_gt(wb.x, wb.y, wb.z, wb.w, area_j, b))          \
                    k_##k = 0;                                          \
            }
            FOR_K(SCANE_K)
#undef SCANE_K
        }
    }

    // ---- emit rows ----
    __syncthreads();
    if (tid < MAX_BOXES) {
        int bi = s_out[tid];
        int o = OUT_OFF_NMS + c * MAX_BOXES * 3 + tid * 3;
        if (bi >= 0) {
            out[o + 0] = 0.0f;
            out[o + 1] = (float)c;
            out[o + 2] = (float)bi;
        } else {
            out[o + 0] = -1.0f;
            out[o + 1] = -1.0f;
            out[o + 2] = -1.0f;
        }
    }
}

extern "C" void kernel_launch(void* const* d_in, const int* in_sizes, int n_in,
                              void* d_out, int out_size, void* d_ws,
                              size_t ws_size, hipStream_t stream) {
    const float* boxes = (const float*)d_in[0];   // [N,4] fp32
    const float* scores = (const float*)d_in[1];  // [N,C] fp32
    float* out = (float*)d_out;

    // Single fused launch: NMS blocks read the original (strided) score
    // columns and emit the transposed copy themselves; boxes-copy blocks
    // run concurrently. No inter-kernel dependency remains.
    fused_nms_kernel<<<NUM_CLASSES + CPBLOCKS, NT, 0, stream>>>(boxes, scores,
                                                                out);
}